// Round 15
// baseline (249.553 us; speedup 1.0000x reference)
//
#include <hip/hip_runtime.h>
#include <hip/hip_bf16.h>
#include <stdint.h>

// Problem constants
#define B_   512
#define T_   87
#define C_   512
#define H_   8
#define D_   64
#define BT_  44544        // B_*T_
#define BH_  4096         // B_*H_

typedef __attribute__((ext_vector_type(4))) float f32x4;
typedef __attribute__((ext_vector_type(8))) __bf16 bf16x8;
typedef __attribute__((ext_vector_type(4))) unsigned short u16x4;

__device__ __forceinline__ int mod29(int x) {
  return x < 29 ? x : (x < 58 ? x - 29 : x - 58);
}

// ---------------- converts ----------------

__global__ void convert_x_kernel(const float* __restrict__ x,
                                 __hip_bfloat16* __restrict__ xb, int n4) {
  int stride = gridDim.x * blockDim.x;
  for (int i = blockIdx.x * blockDim.x + threadIdx.x; i < n4; i += stride) {
    f32x4 v = ((const f32x4*)x)[i];
    u16x4 o;
    o.x = __builtin_bit_cast(unsigned short, __float2bfloat16(v.x));
    o.y = __builtin_bit_cast(unsigned short, __float2bfloat16(v.y));
    o.z = __builtin_bit_cast(unsigned short, __float2bfloat16(v.z));
    o.w = __builtin_bit_cast(unsigned short, __float2bfloat16(v.w));
    ((u16x4*)xb)[i] = o;
  }
}

__global__ void convert_w_kernel(const float* __restrict__ Wq, const float* __restrict__ Wk,
                                 const float* __restrict__ Wv, const float* __restrict__ Wp,
                                 const float* __restrict__ bq, const float* __restrict__ bk,
                                 const float* __restrict__ bv,
                                 __hip_bfloat16* __restrict__ wqkv,
                                 __hip_bfloat16* __restrict__ wp,
                                 float* __restrict__ biasc) {
  const int NW = 262144;                 // 512*512
  const int total = 3 * NW + NW + 1536;
  int stride = gridDim.x * blockDim.x;
  for (int i = blockIdx.x * blockDim.x + threadIdx.x; i < total; i += stride) {
    if (i < 3 * NW) {
      float v = (i < NW) ? Wq[i] : (i < 2 * NW ? Wk[i - NW] : Wv[i - 2 * NW]);
      wqkv[i] = __float2bfloat16(v);
    } else if (i < 4 * NW) {
      wp[i - 3 * NW] = __float2bfloat16(Wp[i - 3 * NW]);
    } else {
      int j = i - 4 * NW;
      biasc[j] = (j < 512) ? bq[j] : (j < 1024 ? bk[j - 512] : bv[j - 1024]);
    }
  }
}

// ---------------- fused qkv-GEMM + attention per (b,h) ----------------
// Per block: q/k/v = x_b[96x512] @ Wslice[192x512]^T  (acc in regs, W from L2),
// then R12-style attention entirely in LDS, y slice out via bounce.
// LDS map: x dbuf 2x[96][128B] @0/@12288 ; Qs[96x144] @24576 ; Ks @38400 ;
// Vt[64x208] @52224 (end 65536). P [96x208] aliases x @0. Y scratch aliases Qs.
#define FX_O  0
#define FQS_O 24576
#define FKS_O 38400
#define FVT_O 52224
#define FPB_O 0
#define FYS_O 24576

__global__ __launch_bounds__(256) void fused_qa_kernel(
    const __hip_bfloat16* __restrict__ xb, const __hip_bfloat16* __restrict__ wqkv,
    const float* __restrict__ biasc, __hip_bfloat16* __restrict__ y_ws) {
  __shared__ __align__(16) char smem[65536];

  int tid = threadIdx.x, lane = tid & 63, wave = tid >> 6;
  int r16 = lane & 15, r4 = lane >> 4;

  // XCD swizzle: all 8 heads of a batch land on one XCD (x_b L2-hot). 4096%8==0.
  int wg = (blockIdx.x & 7) * 512 + (blockIdx.x >> 3);
  int b = wg >> 3, h = wg & 7;

  const char* xg = (const char*)xb + (size_t)b * 87 * 1024;

  // W B-frag row pointers: wave owns output cols [wave*48, wave*48+48) = frags
  // gf = wave*3+fn ; gf 0-3 q, 4-7 k, 8-11 v ; W row = sel*512 + h*64 + (gf&3)*16 + r16
  const char* wrow[3];
#pragma unroll
  for (int f = 0; f < 3; ++f) {
    int gf = wave * 3 + f;
    int sel = gf >> 2;
    int row = sel * 512 + h * 64 + (gf & 3) * 16 + r16;
    wrow[f] = (const char*)wqkv + (size_t)row * 1024;
  }

  // x staging geometry: thread covers rows rbase+32j (j=0..2), 16B chunk c
  const int rbase = tid >> 3, c = tid & 7;

  f32x4 acc[6][3] = {};

  // prologue: stage x K-tile 0 into buffer 0 (zero pad rows >= 87)
  {
#pragma unroll
    for (int j = 0; j < 3; ++j) {
      int row = rbase + 32 * j;
      bf16x8 v = {};
      if (row < 87) v = *(const bf16x8*)(xg + (size_t)row * 1024 + c * 16);
      *(bf16x8*)(smem + FX_O + row * 128 + ((c ^ (row & 7)) << 4)) = v;
    }
  }
  __syncthreads();

  // K-loop: 8 steps of BK=64 ; A from LDS (dbuf), B direct from L2
#pragma unroll
  for (int kt = 0; kt < 8; ++kt) {
    const int cur = kt & 1;
    bf16x8 rx[3];
    if (kt < 7) {
#pragma unroll
      for (int j = 0; j < 3; ++j) {
        int row = rbase + 32 * j;
        bf16x8 v = {};
        if (row < 87) v = *(const bf16x8*)(xg + (size_t)row * 1024 + (kt + 1) * 128 + c * 16);
        rx[j] = v;
      }
    }
    bf16x8 bw[3][2];
#pragma unroll
    for (int f = 0; f < 3; ++f)
#pragma unroll
      for (int kk = 0; kk < 2; ++kk)
        bw[f][kk] = *(const bf16x8*)(wrow[f] + kt * 128 + kk * 64 + r4 * 16);
    const char* xls = smem + FX_O + cur * 12288;
    __builtin_amdgcn_s_setprio(1);
#pragma unroll
    for (int fm = 0; fm < 6; ++fm) {
      int arow = fm * 16 + r16;
      int cx = (arow & 7) << 4;
      bf16x8 a0 = *(const bf16x8*)(xls + arow * 128 + ((r4 * 16) ^ cx));
      bf16x8 a1 = *(const bf16x8*)(xls + arow * 128 + ((64 + r4 * 16) ^ cx));
#pragma unroll
      for (int fn = 0; fn < 3; ++fn) {
        acc[fm][fn] = __builtin_amdgcn_mfma_f32_16x16x32_bf16(a0, bw[fn][0], acc[fm][fn], 0, 0, 0);
        acc[fm][fn] = __builtin_amdgcn_mfma_f32_16x16x32_bf16(a1, bw[fn][1], acc[fm][fn], 0, 0, 0);
      }
    }
    __builtin_amdgcn_s_setprio(0);
    if (kt < 7) {
#pragma unroll
      for (int j = 0; j < 3; ++j) {
        int row = rbase + 32 * j;
        *(bf16x8*)(smem + FX_O + (cur ^ 1) * 12288 + row * 128 + ((c ^ (row & 7)) << 4)) = rx[j];
      }
    }
    __syncthreads();
  }
  // NOTE: after final barrier, x region is dead (P will alias it)

  // qkv epilogue: acc -> Q/K LDS (144B pitch) and Vt LDS (208B pitch, transposed)
#pragma unroll
  for (int fn = 0; fn < 3; ++fn) {
    int gf = wave * 3 + fn;
    int sel = gf >> 2;
    float bv = biasc[sel * 512 + h * 64 + (gf & 3) * 16 + r16];
    if (sel < 2) {
      int base = (sel == 0) ? FQS_O : FKS_O;
      int cl = (gf & 3) * 16 + r16;
#pragma unroll
      for (int fm = 0; fm < 6; ++fm)
#pragma unroll
        for (int rr = 0; rr < 4; ++rr) {
          int row = fm * 16 + r4 * 4 + rr;
          *(__hip_bfloat16*)(smem + base + row * 144 + cl * 2) =
              __float2bfloat16(acc[fm][fn][rr] + bv);
        }
    } else {
      int d = (gf & 3) * 16 + r16;
      int dx = (d >> 3) & 3;
#pragma unroll
      for (int fm = 0; fm < 6; ++fm)
#pragma unroll
        for (int rr = 0; rr < 4; ++rr) {
          int t = fm * 16 + r4 * 4 + rr;
          *(__hip_bfloat16*)(smem + FVT_O + d * 208 + (((t >> 3) ^ dx) << 4) + (t & 7) * 2) =
              __float2bfloat16(acc[fm][fn][rr] + bv);
        }
    }
  }
  __syncthreads();

  // ---- attention (R12-verified structure) ----
  int ljv[6]; bool cok[6];
#pragma unroll
  for (int j = 0; j < 6; ++j) {
    int col = j * 16 + r16;
    ljv[j] = mod29(col);
    cok[j] = col < 87;
  }

  for (int m = wave; m < 6; m += 4) {
    f32x4 s[6] = {};
#pragma unroll
    for (int kk = 0; kk < 2; ++kk) {
      bf16x8 aq = *(const bf16x8*)(smem + FQS_O + (m * 16 + r16) * 144 + kk * 64 + r4 * 16);
#pragma unroll
      for (int j = 0; j < 6; ++j) {
        bf16x8 kb = *(const bf16x8*)(smem + FKS_O + (j * 16 + r16) * 144 + kk * 64 + r4 * 16);
        s[j] = __builtin_amdgcn_mfma_f32_16x16x32_bf16(aq, kb, s[j], 0, 0, 0);
      }
    }
#pragma unroll
    for (int rr = 0; rr < 4; ++rr) {
      int row = m * 16 + r4 * 4 + rr;
      bool rok = row < 87;
      int lr = mod29(row);
      float mxv = -1e30f;
#pragma unroll
      for (int j = 0; j < 6; ++j) {
        bool al = rok && cok[j] && (ljv[j] <= lr) && (ljv[j] + 21 >= lr);
        float sv = al ? s[j][rr] * 0.125f : -1e30f;
        s[j][rr] = sv;
        mxv = fmaxf(mxv, sv);
      }
      mxv = fmaxf(mxv, __shfl_xor(mxv, 1));
      mxv = fmaxf(mxv, __shfl_xor(mxv, 2));
      mxv = fmaxf(mxv, __shfl_xor(mxv, 4));
      mxv = fmaxf(mxv, __shfl_xor(mxv, 8));
      float sm = 0.f;
#pragma unroll
      for (int j = 0; j < 6; ++j) {
        float e = __expf(s[j][rr] - mxv);
        s[j][rr] = e;
        sm += e;
      }
      sm += __shfl_xor(sm, 1);
      sm += __shfl_xor(sm, 2);
      sm += __shfl_xor(sm, 4);
      sm += __shfl_xor(sm, 8);
      float inv = rok ? 1.f / sm : 0.f;
#pragma unroll
      for (int j = 0; j < 6; ++j)
        *(__hip_bfloat16*)(smem + FPB_O + row * 208 + (j * 16 + r16) * 2) =
            __float2bfloat16(s[j][rr] * inv);
    }
  }
  __syncthreads();

  // Y = P V -> LDS scratch (aliases Qs) -> coalesced store
  for (int p = 0; p < 6; ++p) {
    int pair = wave + p * 4;
    int mt = pair >> 2, nt = pair & 3;
    int d = nt * 16 + r16;
    int dx = (d >> 3) & 3;
    f32x4 a2 = {0.f, 0.f, 0.f, 0.f};
#pragma unroll
    for (int kk = 0; kk < 3; ++kk) {
      bf16x8 a  = *(const bf16x8*)(smem + FPB_O + (mt * 16 + r16) * 208 + kk * 64 + r4 * 16);
      bf16x8 bb = *(const bf16x8*)(smem + FVT_O + d * 208 + (((kk * 4 + r4) ^ dx) << 4));
      a2 = __builtin_amdgcn_mfma_f32_16x16x32_bf16(a, bb, a2, 0, 0, 0);
    }
    int t0 = mt * 16 + r4 * 4;
#pragma unroll
    for (int r = 0; r < 4; ++r)
      *(__hip_bfloat16*)(smem + FYS_O + (t0 + r) * 136 + d * 2) = __float2bfloat16(a2[r]);
  }
  __syncthreads();

  for (int i = tid; i < 768; i += 256) {
    int row = i >> 3, ch = i & 7;
    if (row < 87) {
      bf16x8 vrow = *(const bf16x8*)(smem + FYS_O + row * 136 + ch * 16);
      *(bf16x8*)((char*)y_ws + ((size_t)b * 87 + row) * 1024 + h * 128 + ch * 16) = vrow;
    }
  }
}

// ---------------- proj GEMM (R14 core, EPI fp32) -----------------------------
template<int FM, int FN>
__device__ __forceinline__ void compute_tile(const char* Ab, const char* Bb,
                                             int wbM, int wbN, int r16, int r4,
                                             f32x4 acc[FM][FN]) {
  const int cxor = (r16 & 7) << 4;
  bf16x8 bf[FN][2];
#pragma unroll
  for (int fn = 0; fn < FN; ++fn) {
    int row = wbN + fn * 16 + r16;
#pragma unroll
    for (int kk = 0; kk < 2; ++kk)
      bf[fn][kk] = *(const bf16x8*)(Bb + row * 128 + ((kk * 64 + r4 * 16) ^ cxor));
  }
#pragma unroll
  for (int fm = 0; fm < FM; ++fm) {
    int row = wbM + fm * 16 + r16;
    bf16x8 a0 = *(const bf16x8*)(Ab + row * 128 + ((r4 * 16) ^ cxor));
    bf16x8 a1 = *(const bf16x8*)(Ab + row * 128 + ((64 + r4 * 16) ^ cxor));
#pragma unroll
    for (int fn = 0; fn < FN; ++fn) {
      acc[fm][fn] = __builtin_amdgcn_mfma_f32_16x16x32_bf16(a0, bf[fn][0], acc[fm][fn], 0, 0, 0);
      acc[fm][fn] = __builtin_amdgcn_mfma_f32_16x16x32_bf16(a1, bf[fn][1], acc[fm][fn], 0, 0, 0);
    }
  }
}

__global__ __launch_bounds__(256) void gemmr_kernel(
    const __hip_bfloat16* __restrict__ A, const __hip_bfloat16* __restrict__ Bt,
    const float* __restrict__ bias, int ntn, float* __restrict__ out) {
  __shared__ __align__(16) char smem[2][2][16384];

  int tid = threadIdx.x, lane = tid & 63, wave = tid >> 6;
  int r16 = lane & 15, r4 = lane >> 4;

  int nwg = gridDim.x;
  int wg = (blockIdx.x & 7) * (nwg >> 3) + (blockIdx.x >> 3);
  int tileM = (wg / ntn) * 128, tileN = (wg % ntn) * 128;

  int wr = wave >> 1, wc = wave & 1;
  int wbM = wr * 64, wbN = wc * 64;

  const int rbase = tid >> 3, c = tid & 7;
  const int cs = (c ^ (rbase & 7)) << 4;
  const char* Ag = (const char*)A + (size_t)(tileM + rbase) * 1024 + c * 16;
  const char* Bg = (const char*)Bt + (size_t)(tileN + rbase) * 1024 + c * 16;

  f32x4 acc[4][4] = {};
  bf16x8 rA[4], rB[4];

#pragma unroll
  for (int j = 0; j < 4; ++j) {
    rA[j] = *(const bf16x8*)(Ag + (size_t)j * 32768);
    rB[j] = *(const bf16x8*)(Bg + (size_t)j * 32768);
  }
#pragma unroll
  for (int j = 0; j < 4; ++j) {
    *(bf16x8*)(&smem[0][0][0] + (rbase + 32 * j) * 128 + cs) = rA[j];
    *(bf16x8*)(&smem[0][1][0] + (rbase + 32 * j) * 128 + cs) = rB[j];
  }
  __syncthreads();

#pragma unroll
  for (int kt = 0; kt < 8; ++kt) {
    int cur = kt & 1;
    if (kt < 7) {
#pragma unroll
      for (int j = 0; j < 4; ++j) {
        rA[j] = *(const bf16x8*)(Ag + (size_t)j * 32768 + (kt + 1) * 128);
        rB[j] = *(const bf16x8*)(Bg + (size_t)j * 32768 + (kt + 1) * 128);
      }
    }
    __builtin_amdgcn_s_setprio(1);
    compute_tile<4, 4>(&smem[cur][0][0], &smem[cur][1][0], wbM, wbN, r16, r4, acc);
    __builtin_amdgcn_s_setprio(0);
    if (kt < 7) {
#pragma unroll
      for (int j = 0; j < 4; ++j) {
        *(bf16x8*)(&smem[cur ^ 1][0][0] + (rbase + 32 * j) * 128 + cs) = rA[j];
        *(bf16x8*)(&smem[cur ^ 1][1][0] + (rbase + 32 * j) * 128 + cs) = rB[j];
      }
    }
    __syncthreads();
  }

  {
    char* scratch = &smem[0][0][0] + wave * 4352;      // 16 rows x 272B
#pragma unroll
    for (int fm = 0; fm < 4; ++fm) {
#pragma unroll
      for (int fn = 0; fn < 4; ++fn) {
        float bv = bias[tileN + wbN + fn * 16 + r16];
#pragma unroll
        for (int rr = 0; rr < 4; ++rr)
          *(float*)(scratch + (r4 * 4 + rr) * 272 + (fn * 16 + r16) * 4) =
              acc[fm][fn][rr] + bv;
      }
#pragma unroll
      for (int p = 0; p < 4; ++p) {
        f32x4 vr = *(const f32x4*)(scratch + (p * 4 + (lane >> 4)) * 272 + (lane & 15) * 16);
        int gm = tileM + wbM + fm * 16 + p * 4 + (lane >> 4);
        *(f32x4*)(out + (size_t)gm * 512 + tileN + wbN + (lane & 15) * 4) = vr;
      }
    }
  }
}

// ---------------- launch ----------------
extern "C" void kernel_launch(void* const* d_in, const int* in_sizes, int n_in,
                              void* d_out, int out_size, void* d_ws, size_t ws_size,
                              hipStream_t stream) {
  const float* x  = (const float*)d_in[0];
  const float* Wq = (const float*)d_in[1];
  const float* bq = (const float*)d_in[2];
  const float* Wk = (const float*)d_in[3];
  const float* bk = (const float*)d_in[4];
  const float* Wv = (const float*)d_in[5];
  const float* bv = (const float*)d_in[6];
  const float* Wp = (const float*)d_in[7];
  const float* bp = (const float*)d_in[8];
  float* out = (float*)d_out;

  char* ws = (char*)d_ws;
  size_t off = 0;
  __hip_bfloat16* xb    = (__hip_bfloat16*)(ws + off); off += (size_t)BT_ * 512 * 2;
  __hip_bfloat16* yb    = (__hip_bfloat16*)(ws + off); off += (size_t)BT_ * 512 * 2;
  __hip_bfloat16* wqkv  = (__hip_bfloat16*)(ws + off); off += 1536 * 512 * 2;
  __hip_bfloat16* wp    = (__hip_bfloat16*)(ws + off); off += 512 * 512 * 2;
  float*          biasc = (float*)(ws + off);          off += 8192;

  if (ws_size < off) return;

  convert_x_kernel<<<2048, 256, 0, stream>>>(x, xb, BT_ * 512 / 4);
  convert_w_kernel<<<1024, 256, 0, stream>>>(Wq, Wk, Wv, Wp, bq, bk, bv, wqkv, wp, biasc);
  // fused qkv+attn: one block per (b,h)
  fused_qa_kernel<<<BH_, 256, 0, stream>>>(xb, wqkv, biasc, yb);
  // proj: 128x128 tiles -> 348 x 4 = 1392 blocks (div by 8)
  gemmr_kernel<<<1392, 256, 0, stream>>>(yb, wp, bp, 4, out);
}